// Round 14
// baseline (2687.075 us; speedup 1.0000x reference)
//
#include <hip/hip_runtime.h>
#include <math.h>

#define B_N 4096
#define E_N 512
#define C_N 8
#define NU 64
#define BK 16
#define NDEPTH 8
#define MROWS 1536   // NU*BK + E_N
#define THR 0.001f
#define EPSV 1e-8f
#define NTOT (B_N * C_N)   // 32768 score columns
#define WSCALE 64.0f       // lifts W entries (~0.04) out of fp16-subnormal range
#define RSCALE 32.0f       // rho = RSCALE*r; cancels in scores; out = x - rho/32
#define RINV (1.0f / 32.0f)
#define FSP 520            // row stride (floats) for FULL-E (512) transpose tiles
#define BSP 17             // basis stride: proj reads stride-17 -> all-distinct banks
#define ASP 9              // rho [e][c] stride: stride-9 reads -> distinct banks

typedef _Float16 f16;
typedef f16 f16x8 __attribute__((ext_vector_type(8)));
typedef float f32x4 __attribute__((ext_vector_type(4)));

// ---------------- build W (fp16 hi/lo, scaled): W[m][e], m in [0,1536) ------
__global__ void build_w(const float* __restrict__ basis,
                        const float* __restrict__ hasher,
                        f16* __restrict__ whi, f16* __restrict__ wlo) {
  const int m = blockIdx.x;
  const int t = threadIdx.x;
  float a0, a1;
  if (m < NU * BK) {
    const int n = m >> 4, k = m & 15;
    const float* bp = basis + (size_t)n * E_N * BK + k;
    a0 = 0.f; a1 = 0.f;
    for (int e = 0; e < E_N; ++e) {
      const float bv = bp[(size_t)e * BK];
      const float* hrow = hasher + (size_t)e * E_N;
      a0 = fmaf(bv, hrow[t], a0);
      a1 = fmaf(bv, hrow[t + 256], a1);
    }
  } else {
    const int e = m - NU * BK;
    a0 = hasher[(size_t)e * E_N + t];
    a1 = hasher[(size_t)e * E_N + t + 256];
  }
  a0 *= WSCALE; a1 *= WSCALE;
  const f16 h0 = (f16)a0, h1 = (f16)a1;
  whi[(size_t)m * E_N + t] = h0;
  wlo[(size_t)m * E_N + t] = (f16)(a0 - (float)h0);
  whi[(size_t)m * E_N + t + 256] = h1;
  wlo[(size_t)m * E_N + t + 256] = (f16)(a1 - (float)h1);
}

// ---------------- init: x -> rT hi/lo (scaled, transposed) ------------------
__launch_bounds__(256)
__global__ void init_convert(const float* __restrict__ x,
                             f16* __restrict__ rThi, f16* __restrict__ rTlo) {
  __shared__ float TT[C_N * FSP];
  const int tid = threadIdx.x;
  const int b = blockIdx.x;
  const float* xb = x + (size_t)b * E_N * C_N;
  for (int i = tid; i < E_N * C_N / 4; i += 256) {
    const float4 v = ((const float4*)xb)[i];
    const int e = i >> 1, c4 = (i & 1) * 4;
    TT[(c4 + 0) * FSP + e] = v.x;
    TT[(c4 + 1) * FSP + e] = v.y;
    TT[(c4 + 2) * FSP + e] = v.z;
    TT[(c4 + 3) * FSP + e] = v.w;
  }
  __syncthreads();
  const int c = tid >> 5, seg = tid & 31;
  const size_t row = ((size_t)b * C_N + c) * E_N;
#pragma unroll
  for (int hf = 0; hf < 2; ++hf) {
    const int e0 = seg * 16 + hf * 8;
    f16x8 oh, ol;
#pragma unroll
    for (int j = 0; j < 8; ++j) {
      const float v = TT[c * FSP + e0 + j] * RSCALE;
      const f16 h = (f16)v;
      oh[j] = h; ol[j] = (f16)(v - (float)h);
    }
    *(f16x8*)&rThi[row + e0] = oh;
    *(f16x8*)&rTlo[row + e0] = ol;
  }
}

// ---------------- MFMA score kernel (round-10 structure: measured best) -----
// z = W*rT^T via 3-term fp16 split: Whi*rhi + Whi*rlo + Wlo*rhi (fp32 acc).
// 128x128 tile, 4 waves, BK=32, 16 K-steps, reg-prefetch staging (147.7 us;
// DMA-serialized 152, DMA-2-phase 163 -> this is the structural best).
__launch_bounds__(256, 2)
__global__ void mfma_score(const f16* __restrict__ whi, const f16* __restrict__ wlo,
                           const f16* __restrict__ rThi, const f16* __restrict__ rTlo,
                           float* __restrict__ part, float* __restrict__ nupart) {
  __shared__ f16 Ah[128 * 32], Al[128 * 32], Bh[128 * 32], Bl[128 * 32];
  __shared__ float nred[2][128];
  const int tid = threadIdx.x;
  const int lane = tid & 63;
  const int w = tid >> 6, wm = w >> 1, wn = w & 1;
  // XCD-aware swizzle: 3072 blocks = 8 XCDs x 384 (= 32 N-panels x 12 M-tiles)
  const int bid = blockIdx.x;
  const int nid = (bid & 7) * 384 + (bid >> 3);
  const int mt = nid % 12, nt = nid / 12;
  const int m0 = mt * 128;
  const int nq0 = nt * 128;
  const int l15 = lane & 15, lk = lane >> 4;
  const int rsw = lk ^ (l15 & 3) ^ ((l15 >> 2) & 3);   // read chunk swizzle

  const f32x4 fz = {0.f, 0.f, 0.f, 0.f};
  f32x4 acc[4][4];
#pragma unroll
  for (int i = 0; i < 4; ++i)
#pragma unroll
    for (int j = 0; j < 4; ++j) acc[i][j] = fz;

  const int h0 = tid, h1 = 256 + tid;
  const int r0 = h0 >> 2, c0 = h0 & 3, r1 = h1 >> 2, c1 = h1 & 3;
  const int s0 = (h0 & ~3) | (c0 ^ (r0 & 3) ^ ((r0 >> 2) & 3));
  const int s1 = (h1 & ~3) | (c1 ^ (r1 & 3) ^ ((r1 >> 2) & 3));
  const size_t aoff0 = (size_t)(m0 + r0) * E_N + c0 * 8;
  const size_t aoff1 = (size_t)(m0 + r1) * E_N + c1 * 8;
  const size_t boff0 = (size_t)(nq0 + r0) * E_N + c0 * 8;
  const size_t boff1 = (size_t)(nq0 + r1) * E_N + c1 * 8;

  f16x8 vah0 = *(const f16x8*)(whi + aoff0);
  f16x8 vah1 = *(const f16x8*)(whi + aoff1);
  f16x8 val0 = *(const f16x8*)(wlo + aoff0);
  f16x8 val1 = *(const f16x8*)(wlo + aoff1);
  f16x8 vbh0 = *(const f16x8*)(rThi + boff0);
  f16x8 vbh1 = *(const f16x8*)(rThi + boff1);
  f16x8 vbl0 = *(const f16x8*)(rTlo + boff0);
  f16x8 vbl1 = *(const f16x8*)(rTlo + boff1);

  for (int ks = 0; ks < 16; ++ks) {
    __syncthreads();
    ((f16x8*)Ah)[s0] = vah0; ((f16x8*)Ah)[s1] = vah1;
    ((f16x8*)Al)[s0] = val0; ((f16x8*)Al)[s1] = val1;
    ((f16x8*)Bh)[s0] = vbh0; ((f16x8*)Bh)[s1] = vbh1;
    ((f16x8*)Bl)[s0] = vbl0; ((f16x8*)Bl)[s1] = vbl1;
    __syncthreads();
    if (ks < 15) {
      const size_t ko = (size_t)(ks + 1) * 32;
      vah0 = *(const f16x8*)(whi + aoff0 + ko);
      vah1 = *(const f16x8*)(whi + aoff1 + ko);
      val0 = *(const f16x8*)(wlo + aoff0 + ko);
      val1 = *(const f16x8*)(wlo + aoff1 + ko);
      vbh0 = *(const f16x8*)(rThi + boff0 + ko);
      vbh1 = *(const f16x8*)(rThi + boff1 + ko);
      vbl0 = *(const f16x8*)(rTlo + boff0 + ko);
      vbl1 = *(const f16x8*)(rTlo + boff1 + ko);
    }
    f16x8 bhf[4], blf[4];
#pragma unroll
    for (int fn = 0; fn < 4; ++fn) {
      const int row = wn * 64 + fn * 16 + l15;
      const int idx = row * 4 + rsw;
      bhf[fn] = ((const f16x8*)Bh)[idx];
      blf[fn] = ((const f16x8*)Bl)[idx];
    }
#pragma unroll
    for (int fm = 0; fm < 4; ++fm) {
      const int row = wm * 64 + fm * 16 + l15;
      const int idx = row * 4 + rsw;
      const f16x8 ahf = ((const f16x8*)Ah)[idx];
      const f16x8 alf = ((const f16x8*)Al)[idx];
#pragma unroll
      for (int fn = 0; fn < 4; ++fn) {
        acc[fm][fn] = __builtin_amdgcn_mfma_f32_16x16x32_f16(ahf, bhf[fn], acc[fm][fn], 0, 0, 0);
        acc[fm][fn] = __builtin_amdgcn_mfma_f32_16x16x32_f16(ahf, blf[fn], acc[fm][fn], 0, 0, 0);
        acc[fm][fn] = __builtin_amdgcn_mfma_f32_16x16x32_f16(alf, bhf[fn], acc[fm][fn], 0, 0, 0);
      }
    }
  }

  // epilogue: C/D frag layout col = lane&15, row = (lane>>4)*4 + reg
  if (m0 < NU * BK) {
#pragma unroll
    for (int fm = 0; fm < 4; ++fm) {
      const int u = (m0 >> 4) + wm * 4 + fm;
#pragma unroll
      for (int fn = 0; fn < 4; ++fn) {
        const f32x4 a = acc[fm][fn];
        float s = a.x * a.x + a.y * a.y + a.z * a.z + a.w * a.w;
        s += __shfl_xor(s, 16);
        s += __shfl_xor(s, 32);   // 16-row (one unit) column sum
        if (lk == 0)
          part[(size_t)u * NTOT + nq0 + wn * 64 + fn * 16 + l15] = s;
      }
    }
  } else {
#pragma unroll
    for (int fn = 0; fn < 4; ++fn) {
      float s = 0.f;
#pragma unroll
      for (int fm = 0; fm < 4; ++fm) {
        const f32x4 a = acc[fm][fn];
        s += a.x * a.x + a.y * a.y + a.z * a.z + a.w * a.w;
      }
      s += __shfl_xor(s, 16);
      s += __shfl_xor(s, 32);
      if (lk == 0) nred[wm][wn * 64 + fn * 16 + l15] = s;
    }
    __syncthreads();
    if (tid < 128)
      nupart[(size_t)((m0 - NU * BK) >> 7) * NTOT + nq0 + tid] =
          nred[0][tid] + nred[1][tid];
  }
}

// ---------------- apply_fused: pick + coeffs + proj, 4 barriers, 512 thr ----
// Phase A: rho load/decode -> rsc[e][c] (+wave0: score+argmax via shfl)
// Phase B: basis stage (once) + per-wave energy butterfly
// Phase C: coeffs partials (k,c2,q) over e-quarters
// Phase D: combine coeffs + activity decision
// Phase E: proj, thread=e (stride-17/9 LDS reads: conflict-free), coalesced
//          f16 stores. rho read from rsc (no reg round-trip needed).
__launch_bounds__(512, 2)
__global__ void apply_fused(const float* __restrict__ basis,
                            f16* __restrict__ rThi, f16* __restrict__ rTlo,
                            const float* __restrict__ part,
                            const float* __restrict__ nupart,
                            unsigned char* __restrict__ used,
                            float* __restrict__ init_energy,
                            const int depth) {
  __shared__ float bsh[E_N * BSP];     // 34.8 KB  basis [e][k], pad 17
  __shared__ float rsc[E_N * ASP];     // 18.4 KB  rho   [e][c], pad 9
  __shared__ float prt[4][BK * C_N];   // 2 KB
  __shared__ float coeffs[BK * C_N];   // 512 B
  __shared__ float ew[8];
  __shared__ int sbu;
  __shared__ int act_sh;
  const int b = blockIdx.x;
  const int tid = threadIdx.x;
  const int c = tid >> 6, seg = tid & 63;   // 8 channels x 64 e-segments
  const int e0 = seg * 8;
  const size_t row = ((size_t)b * C_N + c) * E_N;

  // ---- phase A ----
  if (tid < NU) {   // wave 0: fused pick (scores >= 0; used -> -1 sentinel)
    float scale[C_N];
#pragma unroll
    for (int cc = 0; cc < C_N; ++cc) {
      float nu = 0.f;
#pragma unroll
      for (int t4 = 0; t4 < 4; ++t4)
        nu += nupart[(size_t)t4 * NTOT + b * C_N + cc];   // lane-uniform
      const float inv = 1.f / (sqrtf(nu) + EPSV);
      scale[cc] = inv * inv;
    }
    const float* pu = part + (size_t)tid * NTOT + b * C_N;
    float s = 0.f;
#pragma unroll
    for (int cc = 0; cc < C_N; ++cc) s = fmaf(pu[cc], scale[cc], s);
    if (used[(size_t)b * NU + tid]) s = -1.f;
    int idx = tid;
#pragma unroll
    for (int m = 1; m < 64; m <<= 1) {   // first-max-wins (lowest idx on tie)
      const float os = __shfl_xor(s, m);
      const int oi = __shfl_xor(idx, m);
      if (os > s || (os == s && oi < idx)) { s = os; idx = oi; }
    }
    if (tid == 0) sbu = idx;
  }
  float en = 0.f;
  {  // rho load + decode; rsc[e][c]
    const f16x8 h = *(const f16x8*)&rThi[row + e0];
    const f16x8 l = *(const f16x8*)&rTlo[row + e0];
#pragma unroll
    for (int j = 0; j < 8; ++j) {
      const float v = (float)h[j] + (float)l[j];
      en = fmaf(v, v, en);
      rsc[(e0 + j) * ASP + c] = v;
    }
  }
  __syncthreads();

  // ---- phase B ----
  const int bu = sbu;
  const float* bp = basis + (size_t)bu * E_N * BK;
  for (int i = tid; i < E_N * BK / 4; i += 512) {   // 4 iters
    const float4 wv = ((const float4*)bp)[i];
    const int f0 = i * 4, e = f0 >> 4, k = f0 & 15;
    bsh[e * BSP + k] = wv.x;     bsh[e * BSP + k + 1] = wv.y;
    bsh[e * BSP + k + 2] = wv.z; bsh[e * BSP + k + 3] = wv.w;
  }
#pragma unroll
  for (int m = 1; m < 64; m <<= 1) en += __shfl_xor(en, m);   // wave energy
  if ((tid & 63) == 0) ew[tid >> 6] = en;
  __syncthreads();

  // ---- phase C: coeffs partials (k,c2,q), 128-e chains ----
  {
    const int k = tid >> 5, c2 = (tid >> 2) & 7, q = tid & 3;
    float s = 0.f;
    const int eq = q * 128;
    for (int e = eq; e < eq + 128; ++e)
      s = fmaf(bsh[e * BSP + k], rsc[e * ASP + c2], s);
    prt[q][k * C_N + c2] = s;
  }
  __syncthreads();

  // ---- phase D: combine + activity ----
  if (tid < 128)
    coeffs[tid] = (prt[0][tid] + prt[1][tid]) + (prt[2][tid] + prt[3][tid]);
  if (tid == 128) {
    const float etot = ((ew[0] + ew[1]) + (ew[2] + ew[3])) +
                       ((ew[4] + ew[5]) + (ew[6] + ew[7]));
    float ie;
    if (depth == 0) { ie = etot; init_energy[b] = etot; }
    else ie = init_energy[b];
    act_sh = (etot > THR * ie) ? 1 : 0;
  }
  __syncthreads();

  // ---- phase E: proj (thread = e) ----
  if (act_sh) {
    const int e = tid;
    float bv[BK];
#pragma unroll
    for (int k = 0; k < BK; ++k) bv[k] = bsh[e * BSP + k];
#pragma unroll
    for (int cc = 0; cc < C_N; ++cc) {
      float pv = 0.f;
#pragma unroll
      for (int k = 0; k < BK; ++k) pv = fmaf(bv[k], coeffs[k * C_N + cc], pv);
      const float rv = rsc[e * ASP + cc] - pv;
      const f16 h = (f16)rv;
      rThi[((size_t)b * C_N + cc) * E_N + e] = h;
      rTlo[((size_t)b * C_N + cc) * E_N + e] = (f16)(rv - (float)h);
    }
    if (tid == 0) used[(size_t)b * NU + bu] = 1;
  }
}

// ---------------- finalize: out[b][e][c] = x - (hi+lo)*RINV -----------------
__launch_bounds__(256)
__global__ void finalize2(const float* __restrict__ x,
                          const f16* __restrict__ rThi,
                          const f16* __restrict__ rTlo,
                          float* __restrict__ out) {
  __shared__ float TT[C_N * FSP];
  const int tid = threadIdx.x;
  const int b = blockIdx.x;
  const int c = tid >> 5, seg = tid & 31;
  const size_t row = ((size_t)b * C_N + c) * E_N;
#pragma unroll
  for (int hf = 0; hf < 2; ++hf) {
    const int e0 = seg * 16 + hf * 8;
    const f16x8 h = *(const f16x8*)&rThi[row + e0];
    const f16x8 l = *(const f16x8*)&rTlo[row + e0];
#pragma unroll
    for (int j = 0; j < 8; ++j)
      TT[c * FSP + e0 + j] = (float)h[j] + (float)l[j];
  }
  __syncthreads();
  const float* xb = x + (size_t)b * E_N * C_N;
  float* ob = out + (size_t)b * E_N * C_N;
  for (int i = tid; i < E_N * C_N / 4; i += 256) {
    const float4 xv = ((const float4*)xb)[i];
    const int e = i >> 1, c4 = (i & 1) * 4;
    float4 o;
    o.x = xv.x - TT[(c4 + 0) * FSP + e] * RINV;
    o.y = xv.y - TT[(c4 + 1) * FSP + e] * RINV;
    o.z = xv.z - TT[(c4 + 2) * FSP + e] * RINV;
    o.w = xv.w - TT[(c4 + 3) * FSP + e] * RINV;
    ((float4*)ob)[i] = o;
  }
}

extern "C" void kernel_launch(void* const* d_in, const int* in_sizes, int n_in,
                              void* d_out, int out_size, void* d_ws, size_t ws_size,
                              hipStream_t stream) {
  const float* x      = (const float*)d_in[0];
  const float* basis  = (const float*)d_in[1];
  const float* hasher = (const float*)d_in[2];
  float* out = (float*)d_out;

  // workspace layout (~75.9 MB)
  float* part        = (float*)d_ws;                         // 8 MB
  float* nupart      = part + (size_t)NU * NTOT;             // 512 KB
  float* init_energy = nupart + (size_t)4 * NTOT;            // 16 KB
  f16*   whi         = (f16*)(init_energy + B_N);            // 1.5 MB
  f16*   wlo         = whi + (size_t)MROWS * E_N;            // 1.5 MB
  f16*   rThi        = wlo + (size_t)MROWS * E_N;            // 32 MB
  f16*   rTlo        = rThi + (size_t)NTOT * E_N;            // 32 MB
  unsigned char* used = (unsigned char*)(rTlo + (size_t)NTOT * E_N); // 256 KB

  hipMemsetAsync(used, 0, (size_t)B_N * NU, stream);
  build_w<<<MROWS, 256, 0, stream>>>(basis, hasher, whi, wlo);
  init_convert<<<B_N, 256, 0, stream>>>(x, rThi, rTlo);

  for (int d = 0; d < NDEPTH; ++d) {
    mfma_score<<<3072, 256, 0, stream>>>(whi, wlo, rThi, rTlo, part, nupart);
    apply_fused<<<B_N, 512, 0, stream>>>(basis, rThi, rTlo, part, nupart,
                                         used, init_energy, d);
  }
  finalize2<<<B_N, 256, 0, stream>>>(x, rThi, rTlo, out);
}

// Round 18
// 1767.658 us; speedup vs baseline: 1.5201x; 1.5201x over previous
//
#include <hip/hip_runtime.h>
#include <math.h>

#define B_N 4096
#define E_N 512
#define C_N 8
#define NU 64
#define BK 16
#define NDEPTH 8
#define MROWS 1536   // NU*BK + E_N
#define THR 0.001f
#define EPSV 1e-8f
#define NTOT (B_N * C_N)   // 32768 score columns
#define WSCALE 64.0f       // lifts W entries (~0.04) out of fp16-subnormal range
#define RSCALE 32.0f       // rho = RSCALE*r; cancels in scores; out = x - rho/32
#define RINV (1.0f / 32.0f)
#define FSP 520            // row stride (floats) for FULL-E (512) transpose tiles
#define BSP 17             // basis [e][k] stride: odd -> stride-17 reads all-distinct banks
#define CSP 516            // rho [c][e] stride, FULL-E row (>=512!). 516 % 32 == 4:
                           // same bank residue as the old 260, so the verified bank
                           // math holds. (Round-17 bug: CSP=260 < 512 row extent ->
                           // row overlap + OOB, absmax 6.7 — same class as r8's FSP.)

typedef _Float16 f16;
typedef f16 f16x8 __attribute__((ext_vector_type(8)));
typedef float f32x4 __attribute__((ext_vector_type(4)));

// ---------------- build W (fp16 hi/lo, scaled): W[m][e], m in [0,1536) ------
__global__ void build_w(const float* __restrict__ basis,
                        const float* __restrict__ hasher,
                        f16* __restrict__ whi, f16* __restrict__ wlo) {
  const int m = blockIdx.x;
  const int t = threadIdx.x;
  float a0, a1;
  if (m < NU * BK) {
    const int n = m >> 4, k = m & 15;
    const float* bp = basis + (size_t)n * E_N * BK + k;
    a0 = 0.f; a1 = 0.f;
    for (int e = 0; e < E_N; ++e) {
      const float bv = bp[(size_t)e * BK];
      const float* hrow = hasher + (size_t)e * E_N;
      a0 = fmaf(bv, hrow[t], a0);
      a1 = fmaf(bv, hrow[t + 256], a1);
    }
  } else {
    const int e = m - NU * BK;
    a0 = hasher[(size_t)e * E_N + t];
    a1 = hasher[(size_t)e * E_N + t + 256];
  }
  a0 *= WSCALE; a1 *= WSCALE;
  const f16 h0 = (f16)a0, h1 = (f16)a1;
  whi[(size_t)m * E_N + t] = h0;
  wlo[(size_t)m * E_N + t] = (f16)(a0 - (float)h0);
  whi[(size_t)m * E_N + t + 256] = h1;
  wlo[(size_t)m * E_N + t + 256] = (f16)(a1 - (float)h1);
}

// ---------------- init: x -> rT hi/lo (scaled, transposed) ------------------
__launch_bounds__(256)
__global__ void init_convert(const float* __restrict__ x,
                             f16* __restrict__ rThi, f16* __restrict__ rTlo) {
  __shared__ float TT[C_N * FSP];
  const int tid = threadIdx.x;
  const int b = blockIdx.x;
  const float* xb = x + (size_t)b * E_N * C_N;
  for (int i = tid; i < E_N * C_N / 4; i += 256) {
    const float4 v = ((const float4*)xb)[i];
    const int e = i >> 1, c4 = (i & 1) * 4;
    TT[(c4 + 0) * FSP + e] = v.x;
    TT[(c4 + 1) * FSP + e] = v.y;
    TT[(c4 + 2) * FSP + e] = v.z;
    TT[(c4 + 3) * FSP + e] = v.w;
  }
  __syncthreads();
  const int c = tid >> 5, seg = tid & 31;
  const size_t row = ((size_t)b * C_N + c) * E_N;
#pragma unroll
  for (int hf = 0; hf < 2; ++hf) {
    const int e0 = seg * 16 + hf * 8;
    f16x8 oh, ol;
#pragma unroll
    for (int j = 0; j < 8; ++j) {
      const float v = TT[c * FSP + e0 + j] * RSCALE;
      const f16 h = (f16)v;
      oh[j] = h; ol[j] = (f16)(v - (float)h);
    }
    *(f16x8*)&rThi[row + e0] = oh;
    *(f16x8*)&rTlo[row + e0] = ol;
  }
}

// ---------------- MFMA score kernel (round-10 structure: measured best) -----
// z = W*rT^T via 3-term fp16 split: Whi*rhi + Whi*rlo + Wlo*rhi (fp32 acc).
// 128x128 tile, 4 waves, BK=32, 16 K-steps, reg-prefetch staging (147.7 us;
// DMA-serialized 152, DMA-2-phase 163 -> this is the structural best).
__launch_bounds__(256, 2)
__global__ void mfma_score(const f16* __restrict__ whi, const f16* __restrict__ wlo,
                           const f16* __restrict__ rThi, const f16* __restrict__ rTlo,
                           float* __restrict__ part, float* __restrict__ nupart) {
  __shared__ f16 Ah[128 * 32], Al[128 * 32], Bh[128 * 32], Bl[128 * 32];
  __shared__ float nred[2][128];
  const int tid = threadIdx.x;
  const int lane = tid & 63;
  const int w = tid >> 6, wm = w >> 1, wn = w & 1;
  // XCD-aware swizzle: 3072 blocks = 8 XCDs x 384 (= 32 N-panels x 12 M-tiles)
  const int bid = blockIdx.x;
  const int nid = (bid & 7) * 384 + (bid >> 3);
  const int mt = nid % 12, nt = nid / 12;
  const int m0 = mt * 128;
  const int nq0 = nt * 128;
  const int l15 = lane & 15, lk = lane >> 4;
  const int rsw = lk ^ (l15 & 3) ^ ((l15 >> 2) & 3);   // read chunk swizzle

  const f32x4 fz = {0.f, 0.f, 0.f, 0.f};
  f32x4 acc[4][4];
#pragma unroll
  for (int i = 0; i < 4; ++i)
#pragma unroll
    for (int j = 0; j < 4; ++j) acc[i][j] = fz;

  const int h0 = tid, h1 = 256 + tid;
  const int r0 = h0 >> 2, c0 = h0 & 3, r1 = h1 >> 2, c1 = h1 & 3;
  const int s0 = (h0 & ~3) | (c0 ^ (r0 & 3) ^ ((r0 >> 2) & 3));
  const int s1 = (h1 & ~3) | (c1 ^ (r1 & 3) ^ ((r1 >> 2) & 3));
  const size_t aoff0 = (size_t)(m0 + r0) * E_N + c0 * 8;
  const size_t aoff1 = (size_t)(m0 + r1) * E_N + c1 * 8;
  const size_t boff0 = (size_t)(nq0 + r0) * E_N + c0 * 8;
  const size_t boff1 = (size_t)(nq0 + r1) * E_N + c1 * 8;

  f16x8 vah0 = *(const f16x8*)(whi + aoff0);
  f16x8 vah1 = *(const f16x8*)(whi + aoff1);
  f16x8 val0 = *(const f16x8*)(wlo + aoff0);
  f16x8 val1 = *(const f16x8*)(wlo + aoff1);
  f16x8 vbh0 = *(const f16x8*)(rThi + boff0);
  f16x8 vbh1 = *(const f16x8*)(rThi + boff1);
  f16x8 vbl0 = *(const f16x8*)(rTlo + boff0);
  f16x8 vbl1 = *(const f16x8*)(rTlo + boff1);

  for (int ks = 0; ks < 16; ++ks) {
    __syncthreads();
    ((f16x8*)Ah)[s0] = vah0; ((f16x8*)Ah)[s1] = vah1;
    ((f16x8*)Al)[s0] = val0; ((f16x8*)Al)[s1] = val1;
    ((f16x8*)Bh)[s0] = vbh0; ((f16x8*)Bh)[s1] = vbh1;
    ((f16x8*)Bl)[s0] = vbl0; ((f16x8*)Bl)[s1] = vbl1;
    __syncthreads();
    if (ks < 15) {
      const size_t ko = (size_t)(ks + 1) * 32;
      vah0 = *(const f16x8*)(whi + aoff0 + ko);
      vah1 = *(const f16x8*)(whi + aoff1 + ko);
      val0 = *(const f16x8*)(wlo + aoff0 + ko);
      val1 = *(const f16x8*)(wlo + aoff1 + ko);
      vbh0 = *(const f16x8*)(rThi + boff0 + ko);
      vbh1 = *(const f16x8*)(rThi + boff1 + ko);
      vbl0 = *(const f16x8*)(rTlo + boff0 + ko);
      vbl1 = *(const f16x8*)(rTlo + boff1 + ko);
    }
    f16x8 bhf[4], blf[4];
#pragma unroll
    for (int fn = 0; fn < 4; ++fn) {
      const int row = wn * 64 + fn * 16 + l15;
      const int idx = row * 4 + rsw;
      bhf[fn] = ((const f16x8*)Bh)[idx];
      blf[fn] = ((const f16x8*)Bl)[idx];
    }
#pragma unroll
    for (int fm = 0; fm < 4; ++fm) {
      const int row = wm * 64 + fm * 16 + l15;
      const int idx = row * 4 + rsw;
      const f16x8 ahf = ((const f16x8*)Ah)[idx];
      const f16x8 alf = ((const f16x8*)Al)[idx];
#pragma unroll
      for (int fn = 0; fn < 4; ++fn) {
        acc[fm][fn] = __builtin_amdgcn_mfma_f32_16x16x32_f16(ahf, bhf[fn], acc[fm][fn], 0, 0, 0);
        acc[fm][fn] = __builtin_amdgcn_mfma_f32_16x16x32_f16(ahf, blf[fn], acc[fm][fn], 0, 0, 0);
        acc[fm][fn] = __builtin_amdgcn_mfma_f32_16x16x32_f16(alf, bhf[fn], acc[fm][fn], 0, 0, 0);
      }
    }
  }

  // epilogue: C/D frag layout col = lane&15, row = (lane>>4)*4 + reg
  if (m0 < NU * BK) {
#pragma unroll
    for (int fm = 0; fm < 4; ++fm) {
      const int u = (m0 >> 4) + wm * 4 + fm;
#pragma unroll
      for (int fn = 0; fn < 4; ++fn) {
        const f32x4 a = acc[fm][fn];
        float s = a.x * a.x + a.y * a.y + a.z * a.z + a.w * a.w;
        s += __shfl_xor(s, 16);
        s += __shfl_xor(s, 32);   // 16-row (one unit) column sum
        if (lk == 0)
          part[(size_t)u * NTOT + nq0 + wn * 64 + fn * 16 + l15] = s;
      }
    }
  } else {
#pragma unroll
    for (int fn = 0; fn < 4; ++fn) {
      float s = 0.f;
#pragma unroll
      for (int fm = 0; fm < 4; ++fm) {
        const f32x4 a = acc[fm][fn];
        s += a.x * a.x + a.y * a.y + a.z * a.z + a.w * a.w;
      }
      s += __shfl_xor(s, 16);
      s += __shfl_xor(s, 32);
      if (lk == 0) nred[wm][wn * 64 + fn * 16 + l15] = s;
    }
    __syncthreads();
    if (tid < 128)
      nupart[(size_t)((m0 - NU * BK) >> 7) * NTOT + nq0 + tid] =
          nred[0][tid] + nred[1][tid];
  }
}

// ---------------- apply_fused2: pick + coeffs + proj, 4 barriers, 512 thr ---
// Bank-verified layouts:
//  rho:  rsc[c][e], stride CSP=516 (>=512 extent; % 32 == 4).
//    A-phase writes: wave c writes consecutive float4s -> conflict-free.
//    C-phase reads (thread k,c2,q; chain e = q+4i): bank = (4*c2+q+4i)%32,
//      (c2,q) covers all 32 banks exactly -> conflict-free, k-pairs broadcast.
//    E-phase reads (thread=e): consecutive -> free.
//  basis: bsh[e][k], stride BSP=17 (odd).
//    C-phase: bank = (17q+k+4i)%32 -> 8 distinct, 8-lane broadcast -> free.
//    E-phase: stride-17 -> all-distinct banks.
__launch_bounds__(512, 2)
__global__ void apply_fused2(const float* __restrict__ basis,
                             f16* __restrict__ rThi, f16* __restrict__ rTlo,
                             const float* __restrict__ part,
                             const float* __restrict__ nupart,
                             unsigned char* __restrict__ used,
                             float* __restrict__ init_energy,
                             const int depth) {
  __shared__ float bsh[E_N * BSP];     // 34.8 KB  basis [e][k], pad 17
  __shared__ float rsc[C_N * CSP];     // 16.5 KB  rho   [c][e], stride 516
  __shared__ float prt[4][BK * C_N];   // 2 KB
  __shared__ float coeffs[BK * C_N];   // 512 B
  __shared__ float ew[8];
  __shared__ int sbu;
  __shared__ int act_sh;
  const int b = blockIdx.x;
  const int tid = threadIdx.x;
  const int c = tid >> 6, seg = tid & 63;   // 8 channels x 64 e-segments
  const int e0 = seg * 8;
  const size_t row = ((size_t)b * C_N + c) * E_N;

  // ---- phase A: rho load/decode -> rsc[c][e]; wave 0 also does pick ----
  if (tid < NU) {   // fused pick (scores >= 0; used -> -1 sentinel)
    float scale[C_N];
#pragma unroll
    for (int cc = 0; cc < C_N; ++cc) {
      float nu = 0.f;
#pragma unroll
      for (int t4 = 0; t4 < 4; ++t4)
        nu += nupart[(size_t)t4 * NTOT + b * C_N + cc];   // lane-uniform
      const float inv = 1.f / (sqrtf(nu) + EPSV);
      scale[cc] = inv * inv;
    }
    const float* pu = part + (size_t)tid * NTOT + b * C_N;
    float s = 0.f;
#pragma unroll
    for (int cc = 0; cc < C_N; ++cc) s = fmaf(pu[cc], scale[cc], s);
    if (used[(size_t)b * NU + tid]) s = -1.f;
    int idx = tid;
#pragma unroll
    for (int m = 1; m < 64; m <<= 1) {   // first-max-wins (lowest idx on tie)
      const float os = __shfl_xor(s, m);
      const int oi = __shfl_xor(idx, m);
      if (os > s || (os == s && oi < idx)) { s = os; idx = oi; }
    }
    if (tid == 0) sbu = idx;
  }
  float en = 0.f;
  {  // rho load + decode; rsc[c][e] (consecutive float4 writes per wave)
    const f16x8 h = *(const f16x8*)&rThi[row + e0];
    const f16x8 l = *(const f16x8*)&rTlo[row + e0];
    float v4a[4], v4b[4];
#pragma unroll
    for (int j = 0; j < 4; ++j) {
      const float v = (float)h[j] + (float)l[j];
      v4a[j] = v; en = fmaf(v, v, en);
    }
#pragma unroll
    for (int j = 0; j < 4; ++j) {
      const float v = (float)h[4 + j] + (float)l[4 + j];
      v4b[j] = v; en = fmaf(v, v, en);
    }
    *(float4*)&rsc[c * CSP + e0]     = *(float4*)v4a;
    *(float4*)&rsc[c * CSP + e0 + 4] = *(float4*)v4b;
  }
  __syncthreads();

  // ---- phase B: basis stage (once) + per-wave energy butterfly ----
  const int bu = sbu;
  const float* bp = basis + (size_t)bu * E_N * BK;
  for (int i = tid; i < E_N * BK / 4; i += 512) {   // 4 iters
    const float4 wv = ((const float4*)bp)[i];
    const int f0 = i * 4, e = f0 >> 4, k = f0 & 15;
    bsh[e * BSP + k] = wv.x;     bsh[e * BSP + k + 1] = wv.y;
    bsh[e * BSP + k + 2] = wv.z; bsh[e * BSP + k + 3] = wv.w;
  }
#pragma unroll
  for (int m = 1; m < 64; m <<= 1) en += __shfl_xor(en, m);   // wave energy
  if ((tid & 63) == 0) ew[tid >> 6] = en;
  __syncthreads();

  // ---- phase C: coeffs partials (k,c2,q), interleaved chains e = q+4i ----
  {
    const int k = tid >> 5, c2 = (tid >> 2) & 7, q = tid & 3;
    float s = 0.f;
    for (int i = 0; i < 128; ++i) {
      const int e = q + 4 * i;
      s = fmaf(bsh[e * BSP + k], rsc[c2 * CSP + e], s);
    }
    prt[q][k * C_N + c2] = s;
  }
  __syncthreads();

  // ---- phase D: combine + activity ----
  if (tid < 128)
    coeffs[tid] = (prt[0][tid] + prt[1][tid]) + (prt[2][tid] + prt[3][tid]);
  if (tid == 128) {
    const float etot = ((ew[0] + ew[1]) + (ew[2] + ew[3])) +
                       ((ew[4] + ew[5]) + (ew[6] + ew[7]));
    float ie;
    if (depth == 0) { ie = etot; init_energy[b] = etot; }
    else ie = init_energy[b];
    act_sh = (etot > THR * ie) ? 1 : 0;
  }
  __syncthreads();

  // ---- phase E: proj (thread = e) ----
  if (act_sh) {
    const int e = tid;
    float bv[BK];
#pragma unroll
    for (int k = 0; k < BK; ++k) bv[k] = bsh[e * BSP + k];  // stride-17: clean
#pragma unroll
    for (int cc = 0; cc < C_N; ++cc) {
      float pv = 0.f;
#pragma unroll
      for (int k = 0; k < BK; ++k) pv = fmaf(bv[k], coeffs[k * C_N + cc], pv);
      const float rv = rsc[cc * CSP + e] - pv;   // consecutive lanes: clean
      const f16 h = (f16)rv;
      rThi[((size_t)b * C_N + cc) * E_N + e] = h;
      rTlo[((size_t)b * C_N + cc) * E_N + e] = (f16)(rv - (float)h);
    }
    if (tid == 0) used[(size_t)b * NU + bu] = 1;
  }
}

// ---------------- finalize: out[b][e][c] = x - (hi+lo)*RINV -----------------
__launch_bounds__(256)
__global__ void finalize2(const float* __restrict__ x,
                          const f16* __restrict__ rThi,
                          const f16* __restrict__ rTlo,
                          float* __restrict__ out) {
  __shared__ float TT[C_N * FSP];
  const int tid = threadIdx.x;
  const int b = blockIdx.x;
  const int c = tid >> 5, seg = tid & 31;
  const size_t row = ((size_t)b * C_N + c) * E_N;
#pragma unroll
  for (int hf = 0; hf < 2; ++hf) {
    const int e0 = seg * 16 + hf * 8;
    const f16x8 h = *(const f16x8*)&rThi[row + e0];
    const f16x8 l = *(const f16x8*)&rTlo[row + e0];
#pragma unroll
    for (int j = 0; j < 8; ++j)
      TT[c * FSP + e0 + j] = (float)h[j] + (float)l[j];
  }
  __syncthreads();
  const float* xb = x + (size_t)b * E_N * C_N;
  float* ob = out + (size_t)b * E_N * C_N;
  for (int i = tid; i < E_N * C_N / 4; i += 256) {
    const float4 xv = ((const float4*)xb)[i];
    const int e = i >> 1, c4 = (i & 1) * 4;
    float4 o;
    o.x = xv.x - TT[(c4 + 0) * FSP + e] * RINV;
    o.y = xv.y - TT[(c4 + 1) * FSP + e] * RINV;
    o.z = xv.z - TT[(c4 + 2) * FSP + e] * RINV;
    o.w = xv.w - TT[(c4 + 3) * FSP + e] * RINV;
    ((float4*)ob)[i] = o;
  }
}

extern "C" void kernel_launch(void* const* d_in, const int* in_sizes, int n_in,
                              void* d_out, int out_size, void* d_ws, size_t ws_size,
                              hipStream_t stream) {
  const float* x      = (const float*)d_in[0];
  const float* basis  = (const float*)d_in[1];
  const float* hasher = (const float*)d_in[2];
  float* out = (float*)d_out;

  // workspace layout (~75.9 MB)
  float* part        = (float*)d_ws;                         // 8 MB
  float* nupart      = part + (size_t)NU * NTOT;             // 512 KB
  float* init_energy = nupart + (size_t)4 * NTOT;            // 16 KB
  f16*   whi         = (f16*)(init_energy + B_N);            // 1.5 MB
  f16*   wlo         = whi + (size_t)MROWS * E_N;            // 1.5 MB
  f16*   rThi        = wlo + (size_t)MROWS * E_N;            // 32 MB
  f16*   rTlo        = rThi + (size_t)NTOT * E_N;            // 32 MB
  unsigned char* used = (unsigned char*)(rTlo + (size_t)NTOT * E_N); // 256 KB

  hipMemsetAsync(used, 0, (size_t)B_N * NU, stream);
  build_w<<<MROWS, 256, 0, stream>>>(basis, hasher, whi, wlo);
  init_convert<<<B_N, 256, 0, stream>>>(x, rThi, rTlo);

  for (int d = 0; d < NDEPTH; ++d) {
    mfma_score<<<3072, 256, 0, stream>>>(whi, wlo, rThi, rTlo, part, nupart);
    apply_fused2<<<B_N, 512, 0, stream>>>(basis, rThi, rTlo, part, nupart,
                                          used, init_energy, d);
  }
  finalize2<<<B_N, 256, 0, stream>>>(x, rThi, rTlo, out);
}